// Round 1
// 400.420 us; speedup vs baseline: 1.0046x; 1.0046x over previous
//
#include <hip/hip_runtime.h>

// SparseCrop: mask = all(10 <= coords[:, :3] < 90); out = (feats * mask, mask)
// Memory-bound. 16 threads per row, one float4 per thread.
// Masked-out rows (~48.8%) skip the feats load entirely (exec-mask predication
// suppresses the fetch), saving ~125 MB of HBM reads.
// R3: non-temporal loads/stores via native clang vector type.
// R4: grid-stride loop, 2048 blocks x 256 threads (= full machine residency,
//     256 CU x 2048 threads). Amortizes block launch/retire churn across ~30
//     iterations/thread; each grid sweep covers a contiguous 8 MB span.

typedef float vfloat4 __attribute__((ext_vector_type(4)));

__global__ __launch_bounds__(256) void sparse_crop_kernel(
    const int4* __restrict__ coords,       // (N) int4 per row
    const vfloat4* __restrict__ feats,     // (N*16) float4
    vfloat4* __restrict__ out_feats,       // (N*16) float4
    float* __restrict__ out_mask,          // (N) floats (bool as 0.0/1.0)
    int total)                             // n * 16 float4-elements
{
    const int stride = gridDim.x * blockDim.x;
    for (int i = blockIdx.x * blockDim.x + threadIdx.x; i < total; i += stride) {
        const int row = i >> 4;
        const int col = i & 15;

        int4 c = coords[row];  // 16B aligned; 16 lanes/row hit the same line
        // 10 <= x < 90  <=>  (unsigned)(x - 10) < 80
        bool m = ((unsigned)(c.x - 10) < 80u) &
                 ((unsigned)(c.y - 10) < 80u) &
                 ((unsigned)(c.z - 10) < 80u);

        vfloat4 v = (vfloat4)(0.f);
        if (m) {
            // predicated: masked rows never fetch; nt: streamed once
            v = __builtin_nontemporal_load(&feats[i]);
        }
        __builtin_nontemporal_store(v, &out_feats[i]);

        if (col == 0) {
            __builtin_nontemporal_store(m ? 1.0f : 0.0f, &out_mask[row]);
        }
    }
}

extern "C" void kernel_launch(void* const* d_in, const int* in_sizes, int n_in,
                              void* d_out, int out_size, void* d_ws, size_t ws_size,
                              hipStream_t stream) {
    const int4* coords   = (const int4*)d_in[0];    // (N,4) int32
    const vfloat4* feats = (const vfloat4*)d_in[1]; // (N,64) fp32

    int n = in_sizes[0] / 4;              // N = 1,000,000
    float* out = (float*)d_out;
    vfloat4* out_feats = (vfloat4*)out;             // first N*64 floats
    float* out_mask    = out + (size_t)n * 64;      // next N floats

    int total = n * 16;                   // 16M float4 work-items
    int blocks = (total + 255) / 256;
    if (blocks > 2048) blocks = 2048;     // grid-stride the rest (G11)
    sparse_crop_kernel<<<blocks, 256, 0, stream>>>(coords, feats, out_feats, out_mask, total);
}

// Round 2
// 399.740 us; speedup vs baseline: 1.0063x; 1.0017x over previous
//
#include <hip/hip_runtime.h>

// SparseCrop: mask = all(10 <= coords[:, :3] < 90); out = (feats * mask, mask)
// Memory-bound. Two grid-stride passes in one dispatch:
//   Pass 1 (mask): lane i -> row i. 64 consecutive dwords per wave = 4 full
//     64B lines, coalesced within a single wave/XCD. (Previously col==0 lanes
//     wrote scattered dwords; each mask line was assembled from 16 different
//     waves across XCDs -> partial-line HBM read-modify-write amplification.)
//   Pass 2 (feats): 16 threads per row, one float4 per thread. Masked-out rows
//     (~48.8%) skip the feats load via exec-mask predication (~125 MB saved).
//     coords re-read in pass 2 hits L3 (16 MB, Infinity-Cache-resident).
// R3: non-temporal loads/stores via native clang vector type.
// R4: grid-stride loop, 2048 blocks x 256 threads (full machine residency).
// R5: split mask writes into a coalesced pass (this version).

typedef float vfloat4 __attribute__((ext_vector_type(4)));

__device__ __forceinline__ bool in_crop(int4 c) {
    // 10 <= x < 90  <=>  (unsigned)(x - 10) < 80
    return ((unsigned)(c.x - 10) < 80u) &
           ((unsigned)(c.y - 10) < 80u) &
           ((unsigned)(c.z - 10) < 80u);
}

__global__ __launch_bounds__(256) void sparse_crop_kernel(
    const int4* __restrict__ coords,       // (N) int4 per row
    const vfloat4* __restrict__ feats,     // (N*16) float4
    vfloat4* __restrict__ out_feats,       // (N*16) float4
    float* __restrict__ out_mask,          // (N) floats (bool as 0.0/1.0)
    int n)                                 // number of rows
{
    const int stride = gridDim.x * blockDim.x;
    const int tid0 = blockIdx.x * blockDim.x + threadIdx.x;

    // ---- Pass 1: mask, fully coalesced (64 consecutive rows per wave) ----
    for (int r = tid0; r < n; r += stride) {
        int4 c = coords[r];
        __builtin_nontemporal_store(in_crop(c) ? 1.0f : 0.0f, &out_mask[r]);
    }

    // ---- Pass 2: feats, 16 lanes per row ----
    const int total = n * 16;
    for (int i = tid0; i < total; i += stride) {
        const int row = i >> 4;

        int4 c = coords[row];  // L3-hot after pass 1; 16 lanes share the line
        bool m = in_crop(c);

        vfloat4 v = (vfloat4)(0.f);
        if (m) {
            // predicated: masked rows never fetch; nt: streamed once
            v = __builtin_nontemporal_load(&feats[i]);
        }
        __builtin_nontemporal_store(v, &out_feats[i]);
    }
}

extern "C" void kernel_launch(void* const* d_in, const int* in_sizes, int n_in,
                              void* d_out, int out_size, void* d_ws, size_t ws_size,
                              hipStream_t stream) {
    const int4* coords   = (const int4*)d_in[0];    // (N,4) int32
    const vfloat4* feats = (const vfloat4*)d_in[1]; // (N,64) fp32

    int n = in_sizes[0] / 4;              // N = 1,000,000
    float* out = (float*)d_out;
    vfloat4* out_feats = (vfloat4*)out;             // first N*64 floats
    float* out_mask    = out + (size_t)n * 64;      // next N floats

    int total = n * 16;                   // 16M float4 work-items
    int blocks = (total + 255) / 256;
    if (blocks > 2048) blocks = 2048;     // grid-stride the rest (G11)
    sparse_crop_kernel<<<blocks, 256, 0, stream>>>(coords, feats, out_feats, out_mask, n);
}